// Round 19
// baseline (73.749 us; speedup 1.0000x reference)
//
#include <hip/hip_runtime.h>
#include <math.h>
#include <stdint.h>

// IntGELU — interval-hedged pipeline, v19: v18 decision semantics
// (two rows/block, single-division hedge, row-uniform FAST dispatch), plus:
//  - FUSED A/B element loop: 8 independent chains in flight per iteration.
//  - xi = fma(xv, rsf, -xm*rsf): one FMA (deviation <= 1 ulp, inside the
//    hedge's del slack — same budget class as the f32-front-chain drift).
//  - rem2 = min(rem, rem-sH) unsigned-wrap trick (branchless, no cndmask
//    dependency chain).
//  - __launch_bounds__(TPB, 8): pin allocator at 8 waves/SIMD.

constexpr int H    = 3072;
constexpr int TPB  = 256;
constexpr int V4   = H / 4;      // 768 float4 per row
constexpr int PER  = V4 / TPB;   // 3 float4 per thread per row
constexpr int ROWS = 2;          // 12544 = 2 * 6272

constexpr uint32_t MU32      = 2147483647u;
constexpr float    CBIAS     = 2147482880.0f;  // 2^31 - 768
constexpr float    WT2       = 0.19365f * 0.5f;
constexpr uint32_t EMIN_FAST = 1u << 18;       // single-div validity bound

__device__ __forceinline__ float rcpf(float x) {
#if __has_builtin(__builtin_amdgcn_rcpf)
    return __builtin_amdgcn_rcpf(x);
#else
    return 1.0f / x;
#endif
}

__device__ __forceinline__ uint32_t fix_up(uint32_t q, uint32_t s) {
    uint32_t rem = MU32 - q * s;            // q*s <= M -> no wrap
    return q + ((rem >= s) ? 1u : 0u);
}

// front chain with fused xi-FMA: nxm = -xm*rsf precomputed per row
__device__ __forceinline__ float eiarg_f(float xv, float nxm, float rsff,
                                         float mx0f, float n23x0f, float rx0f)
{
    float xi = fmaf(xv, rsff, nxm);         // <= ~0 (1 ulp vs (xv-xm)*rsf)
    float t  = (xi + floorf(xi * 0.5f)) - floorf(xi * 0.0625f);
    t = fmaxf(t, n23x0f);
    int   qi = (int)(t * rx0f);             // q in [0,23]
    float qd = (float)qi;
    float r  = fmaf(mx0f, qd, t);           // t - x0*q
    float e  = fmaf(r, 0.5f, mx0f);         // e in (15, 30]
    return ldexpf(e, 23 - qi);              // v_ldexp_f32
}

template<bool FAST>
__device__ __forceinline__ float elem_fast(float xv, float nxm, float rsff,
                                           float mx0f, float n23x0f, float rx0f,
                                           uint32_t emax_u, uint32_t& dmax)
{
    float eiarg = eiarg_f(xv, nxm, rsff, mx0f, n23x0f, rx0f);
    float del = fmaf(4.4e-6f, eiarg, 8.0f);
    uint32_t uL = (uint32_t)(eiarg - del);
    uint32_t uH = (uint32_t)(eiarg + del);
    uint32_t sL = uL + emax_u;
    uint32_t sH = uH + emax_u;

    uint32_t sigLo, sigHi;
    if (FAST) {
        uint32_t ds  = uH - uL;                      // <= ~2300
        uint32_t q   = (uint32_t)(CBIAS * rcpf((float)sH));  // {Flo-1, Flo}
        uint32_t rem = MU32 - q * sH;                // >= 0, no wrap
        uint32_t Flo = q + ((rem >= sH) ? 1u : 0u);  // exact floor(M/sH)
        uint32_t rem2 = min(rem, rem - sH);          // M - Flo*sH (wrap trick)
        uint32_t fds  = __umul24(ds, Flo);           // exact, < 2^25
        uint32_t c    = (rem2 + fds >= sL) ? 1u : 0u;  // Fhi = Flo + c
        uint32_t P    = uL * Flo;                    // exact u32
        sigLo = P >> 24;
        sigHi = (P + fds + (c ? uH : 0u)) >> 24;     // uH*(Flo+c) exact
    } else {
        uint32_t FH = fix_up((uint32_t)(CBIAS * rcpf((float)sL)), sL);
        uint32_t FL = fix_up((uint32_t)(CBIAS * rcpf((float)sH)), sH);
        sigLo = (uL * FL) >> 24;
        sigHi = (uH * FH) >> 24;
    }
    dmax = max(dmax, sigHi - sigLo);
    return (xv * 0.00390625f) * (float)(sigLo + sigHi);
}

// rare path (wave saw dsig >= 3): exact v10-v18 semantics
__device__ __noinline__ float elem_full(float xv, float nxm, float rsff,
                                        float mx0f, float n23x0f, float rx0f,
                                        uint32_t emax_u)
{
    float eiarg = eiarg_f(xv, nxm, rsff, mx0f, n23x0f, rx0f);
    float del = fmaf(4.4e-6f, eiarg, 8.0f);
    uint32_t uL = (uint32_t)(eiarg - del);
    uint32_t uH = (uint32_t)(eiarg + del);
    uint32_t sL = uL + emax_u;
    uint32_t sH = uH + emax_u;
    uint32_t FH = fix_up((uint32_t)(CBIAS * rcpf((float)sL)), sL);
    uint32_t FL = fix_up((uint32_t)(CBIAS * rcpf((float)sH)), sH);
    uint32_t sigLo = (uL * FL) >> 24;
    uint32_t sigHi = (uH * FH) >> 24;
    float m05 = xv * 0.00390625f;
    float W = fabsf(m05) * (float)(sigHi - sigLo);
    if (W <= WT2) return m05 * (float)(sigLo + sigHi);
    uint32_t ei_u = (uint32_t)eiarg;
    uint32_t sb   = ei_u + emax_u;
    uint32_t fb   = fix_up((uint32_t)(CBIAS * rcpf((float)sb)), sb);
    uint32_t sigb = (ei_u * fb) >> 24;
    return (xv * 0.0078125f) * (float)sigb;
}

template<bool FA, bool FB>
__device__ __forceinline__ void both_rows(const float4* keepA, const float4* keepB,
                                          float4* yb, size_t baseA, size_t baseB,
                                          int tx, float nxA, float nxB,
                                          float rsff, float mx0f, float n23x0f,
                                          float rx0f, uint32_t emaxA,
                                          uint32_t emaxB, uint32_t& dmax)
{
#pragma unroll
    for (int i = 0; i < PER; ++i) {
        float4 a = keepA[i], b = keepB[i], oA, oB;
        oA.x = elem_fast<FA>(a.x, nxA, rsff, mx0f, n23x0f, rx0f, emaxA, dmax);
        oB.x = elem_fast<FB>(b.x, nxB, rsff, mx0f, n23x0f, rx0f, emaxB, dmax);
        oA.y = elem_fast<FA>(a.y, nxA, rsff, mx0f, n23x0f, rx0f, emaxA, dmax);
        oB.y = elem_fast<FB>(b.y, nxB, rsff, mx0f, n23x0f, rx0f, emaxB, dmax);
        oA.z = elem_fast<FA>(a.z, nxA, rsff, mx0f, n23x0f, rx0f, emaxA, dmax);
        oB.z = elem_fast<FB>(b.z, nxB, rsff, mx0f, n23x0f, rx0f, emaxB, dmax);
        oA.w = elem_fast<FA>(a.w, nxA, rsff, mx0f, n23x0f, rx0f, emaxA, dmax);
        oB.w = elem_fast<FB>(b.w, nxB, rsff, mx0f, n23x0f, rx0f, emaxB, dmax);
        yb[baseA + tx + i * TPB] = oA;
        yb[baseB + tx + i * TPB] = oB;
    }
}

__global__ __launch_bounds__(TPB, 8) void ig_ivhedge_v19(
    const float* __restrict__ xin, const float* __restrict__ sfin,
    float* __restrict__ yout, int nrow)
{
    const int tx   = threadIdx.x;
    const int rowA = blockIdx.x * ROWS;
    const int rowB = rowA + 1;

    const float sff    = sfin[0];
    const float rsff   = 1.0f / sff;
    const double x0d   = floor(-1.0 / ((double)sff * 1.702));
    const float mx0f   = (float)(-x0d);              // 30, exact
    const float n23x0f = (float)(23.0 * x0d);        // -690, exact
    const float rx0f   = (float)(1.0 / x0d);
    const float osf    = sff * 0.0078125f;

    const float4* xb = reinterpret_cast<const float4*>(xin);
    float4*       yb = reinterpret_cast<float4*>(yout);
    const size_t baseA = (size_t)rowA * V4;
    const size_t baseB = (size_t)rowB * V4;

    // Load both rows; interleaved lane-max chains.
    float4 keepA[PER], keepB[PER];
    float mxA = -3.402823466e38f, mxB = -3.402823466e38f;
#pragma unroll
    for (int i = 0; i < PER; ++i) {
        float4 a = xb[baseA + tx + i * TPB];
        float4 b = xb[baseB + tx + i * TPB];
        keepA[i] = a; keepB[i] = b;
        mxA = fmaxf(fmaxf(mxA, fmaxf(a.x, a.y)), fmaxf(a.z, a.w));
        mxB = fmaxf(fmaxf(mxB, fmaxf(b.x, b.y)), fmaxf(b.z, b.w));
    }
#pragma unroll
    for (int d = 32; d >= 1; d >>= 1) {
        mxA = fmaxf(mxA, __shfl_xor(mxA, d, 64));
        mxB = fmaxf(mxB, __shfl_xor(mxB, d, 64));
    }
    __shared__ float smx[ROWS][TPB / 64];
    if ((tx & 63) == 0) { smx[0][tx >> 6] = mxA; smx[1][tx >> 6] = mxB; }
    __syncthreads();                       // one barrier for both rows
    float xmA = smx[0][0], xmB = smx[1][0];
#pragma unroll
    for (int wv = 1; wv < TPB / 64; ++wv) {
        xmA = fmaxf(xmA, smx[0][wv]);
        xmB = fmaxf(xmB, smx[1][wv]);
    }

    const float nxA = -xmA * rsff;         // xi(0) = nxm
    const float nxB = -xmB * rsff;
    const uint32_t emaxA =
        (uint32_t)eiarg_f(0.0f, nxA, rsff, mx0f, n23x0f, rx0f);
    const uint32_t emaxB =
        (uint32_t)eiarg_f(0.0f, nxB, rsff, mx0f, n23x0f, rx0f);

    uint32_t dmax = 0u;
    const bool fA = (emaxA >= EMIN_FAST), fB = (emaxB >= EMIN_FAST);
    if (fA && fB)
        both_rows<true , true >(keepA, keepB, yb, baseA, baseB, tx, nxA, nxB,
                                rsff, mx0f, n23x0f, rx0f, emaxA, emaxB, dmax);
    else if (fA)
        both_rows<true , false>(keepA, keepB, yb, baseA, baseB, tx, nxA, nxB,
                                rsff, mx0f, n23x0f, rx0f, emaxA, emaxB, dmax);
    else if (fB)
        both_rows<false, true >(keepA, keepB, yb, baseA, baseB, tx, nxA, nxB,
                                rsff, mx0f, n23x0f, rx0f, emaxA, emaxB, dmax);
    else
        both_rows<false, false>(keepA, keepB, yb, baseA, baseB, tx, nxA, nxB,
                                rsff, mx0f, n23x0f, rx0f, emaxA, emaxB, dmax);

    // dsig<=2 => W <= 2|x|/256 < WT2 for |x|<=12: fallback ~never fires.
    if (__any(dmax >= 3u)) {
#pragma unroll
        for (int i = 0; i < PER; ++i) {
            float4 a = keepA[i], b = keepB[i], oA, oB;
            oA.x = elem_full(a.x, nxA, rsff, mx0f, n23x0f, rx0f, emaxA);
            oA.y = elem_full(a.y, nxA, rsff, mx0f, n23x0f, rx0f, emaxA);
            oA.z = elem_full(a.z, nxA, rsff, mx0f, n23x0f, rx0f, emaxA);
            oA.w = elem_full(a.w, nxA, rsff, mx0f, n23x0f, rx0f, emaxA);
            oB.x = elem_full(b.x, nxB, rsff, mx0f, n23x0f, rx0f, emaxB);
            oB.y = elem_full(b.y, nxB, rsff, mx0f, n23x0f, rx0f, emaxB);
            oB.z = elem_full(b.z, nxB, rsff, mx0f, n23x0f, rx0f, emaxB);
            oB.w = elem_full(b.w, nxB, rsff, mx0f, n23x0f, rx0f, emaxB);
            yb[baseA + tx + i * TPB] = oA;
            yb[baseB + tx + i * TPB] = oB;
        }
    }

    if (blockIdx.x == 0 && tx == 0)
        yout[(size_t)nrow * H] = osf;
}

extern "C" void kernel_launch(void* const* d_in, const int* in_sizes, int n_in,
                              void* d_out, int out_size, void* d_ws, size_t ws_size,
                              hipStream_t stream) {
    const float* x  = (const float*)d_in[0];
    const float* sf = (const float*)d_in[1];
    float* out = (float*)d_out;
    const int total = in_sizes[0];       // 64*196*3072
    const int nrow  = total / H;         // 12544
    const int nblk  = nrow / ROWS;       // 6272
    ig_ivhedge_v19<<<nblk, TPB, 0, stream>>>(x, sf, out, nrow);
}

// Round 20
// 62.388 us; speedup vs baseline: 1.1821x; 1.1821x over previous
//
#include <hip/hip_runtime.h>
#include <math.h>
#include <stdint.h>

// IntGELU — interval-hedged pipeline, v20 == v18 (best: 62.5us), restored
// after v19's fused-store regression (interleaved row-stream stores broke
// write locality: WRITE 151->197MB). Two rows/block, per-row contiguous
// compute+store; single-division hedge:
//  - ONE exact division per element: Flo = floor(M/sH) via CBIAS*rcp + one
//    remainder fixup (estimate provably in {Flo-1, Flo}).
//  - Fhi = Flo + c, c = (rem2 + Flo*ds >= sL): exact integer identity,
//    valid for emax >= 2^18 (then Fhi-Flo <= 1); rare rows below bound
//    use the two-division path (row-uniform template dispatch).
//  - sigHi via uH*Fhi = uL*Flo + ds*Flo + c*uH (exact u32, __umul24 for
//    ds*Flo < 2^25).
//  - fast path branchless midpoint out=(x*2^-8)*(sigLo+sigHi); wave-vote
//    dmax>=3 fallback (dsig<=2 => W < threshold for |x|<=12) ~never fires.

constexpr int H    = 3072;
constexpr int TPB  = 256;
constexpr int V4   = H / 4;      // 768 float4 per row
constexpr int PER  = V4 / TPB;   // 3 float4 per thread per row
constexpr int ROWS = 2;          // 12544 = 2 * 6272

constexpr uint32_t MU32      = 2147483647u;
constexpr float    CBIAS     = 2147482880.0f;  // 2^31 - 768
constexpr float    WT2       = 0.19365f * 0.5f;
constexpr uint32_t EMIN_FAST = 1u << 18;       // single-div validity bound

__device__ __forceinline__ float rcpf(float x) {
#if __has_builtin(__builtin_amdgcn_rcpf)
    return __builtin_amdgcn_rcpf(x);
#else
    return 1.0f / x;
#endif
}

__device__ __forceinline__ uint32_t fix_up(uint32_t q, uint32_t s) {
    uint32_t rem = MU32 - q * s;            // q*s <= M -> no wrap
    return q + ((rem >= s) ? 1u : 0u);
}

__device__ __forceinline__ float eiarg_f(float xv, float xmf, float rsff,
                                         float mx0f, float n23x0f, float rx0f)
{
    float xi = (xv - xmf) * rsff;           // <= ~0
    float t  = (xi + floorf(xi * 0.5f)) - floorf(xi * 0.0625f);
    t = fmaxf(t, n23x0f);
    int   qi = (int)(t * rx0f);             // q in [0,23]
    float qd = (float)qi;
    float r  = fmaf(mx0f, qd, t);           // t - x0*q
    float e  = fmaf(r, 0.5f, mx0f);         // e in (15, 30]
    return ldexpf(e, 23 - qi);              // v_ldexp_f32
}

// FAST=true : single division + derived Fhi (requires emax >= 2^18)
// FAST=false: two-division corners (any emax)
template<bool FAST>
__device__ __forceinline__ float elem_fast(float xv, float xmf, float rsff,
                                           float mx0f, float n23x0f, float rx0f,
                                           uint32_t emax_u, uint32_t& dmax)
{
    float eiarg = eiarg_f(xv, xmf, rsff, mx0f, n23x0f, rx0f);
    float del = fmaf(4.4e-6f, eiarg, 8.0f);
    uint32_t uL = (uint32_t)(eiarg - del);
    uint32_t uH = (uint32_t)(eiarg + del);
    uint32_t sL = uL + emax_u;
    uint32_t sH = uH + emax_u;

    uint32_t sigLo, sigHi;
    if (FAST) {
        uint32_t ds  = uH - uL;                      // <= ~2300
        uint32_t q   = (uint32_t)(CBIAS * rcpf((float)sH));  // {Flo-1, Flo}
        uint32_t rem = MU32 - q * sH;                // >= 0, no wrap
        uint32_t inc = (rem >= sH) ? 1u : 0u;
        uint32_t Flo = q + inc;                      // exact floor(M/sH)
        uint32_t rem2 = rem - (inc ? sH : 0u);       // M - Flo*sH, in [0,sH)
        uint32_t fds  = __umul24(ds, Flo);           // exact, < 2^25
        uint32_t c    = (rem2 + fds >= sL) ? 1u : 0u;  // Fhi = Flo + c
        uint32_t P    = uL * Flo;                    // exact u32
        sigLo = P >> 24;
        sigHi = (P + fds + (c ? uH : 0u)) >> 24;     // uH*(Flo+c) exact
    } else {
        uint32_t FH = fix_up((uint32_t)(CBIAS * rcpf((float)sL)), sL);
        uint32_t FL = fix_up((uint32_t)(CBIAS * rcpf((float)sH)), sH);
        sigLo = (uL * FL) >> 24;
        sigHi = (uH * FH) >> 24;
    }
    dmax = max(dmax, sigHi - sigLo);
    return (xv * 0.00390625f) * (float)(sigLo + sigHi);
}

// rare path (wave saw dsig >= 3): exact v10-v18 semantics
__device__ __noinline__ float elem_full(float xv, float xmf, float rsff,
                                        float mx0f, float n23x0f, float rx0f,
                                        uint32_t emax_u)
{
    float eiarg = eiarg_f(xv, xmf, rsff, mx0f, n23x0f, rx0f);
    float del = fmaf(4.4e-6f, eiarg, 8.0f);
    uint32_t uL = (uint32_t)(eiarg - del);
    uint32_t uH = (uint32_t)(eiarg + del);
    uint32_t sL = uL + emax_u;
    uint32_t sH = uH + emax_u;
    uint32_t FH = fix_up((uint32_t)(CBIAS * rcpf((float)sL)), sL);
    uint32_t FL = fix_up((uint32_t)(CBIAS * rcpf((float)sH)), sH);
    uint32_t sigLo = (uL * FL) >> 24;
    uint32_t sigHi = (uH * FH) >> 24;
    float m05 = xv * 0.00390625f;
    float W = fabsf(m05) * (float)(sigHi - sigLo);
    if (W <= WT2) return m05 * (float)(sigLo + sigHi);
    uint32_t ei_u = (uint32_t)eiarg;
    uint32_t sb   = ei_u + emax_u;
    uint32_t fb   = fix_up((uint32_t)(CBIAS * rcpf((float)sb)), sb);
    uint32_t sigb = (ei_u * fb) >> 24;
    return (xv * 0.0078125f) * (float)sigb;
}

template<bool FAST>
__device__ __forceinline__ void row_pass(const float4* keep, float4* yb,
                                         size_t base, int tx, float xm,
                                         float rsff, float mx0f, float n23x0f,
                                         float rx0f, uint32_t emax_u,
                                         uint32_t& dmax)
{
#pragma unroll
    for (int i = 0; i < PER; ++i) {
        float4 a = keep[i], o;
        o.x = elem_fast<FAST>(a.x, xm, rsff, mx0f, n23x0f, rx0f, emax_u, dmax);
        o.y = elem_fast<FAST>(a.y, xm, rsff, mx0f, n23x0f, rx0f, emax_u, dmax);
        o.z = elem_fast<FAST>(a.z, xm, rsff, mx0f, n23x0f, rx0f, emax_u, dmax);
        o.w = elem_fast<FAST>(a.w, xm, rsff, mx0f, n23x0f, rx0f, emax_u, dmax);
        yb[base + tx + i * TPB] = o;
    }
}

__global__ __launch_bounds__(TPB) void ig_ivhedge_v20(
    const float* __restrict__ xin, const float* __restrict__ sfin,
    float* __restrict__ yout, int nrow)
{
    const int tx   = threadIdx.x;
    const int rowA = blockIdx.x * ROWS;
    const int rowB = rowA + 1;

    const float sff    = sfin[0];
    const float rsff   = 1.0f / sff;
    const double x0d   = floor(-1.0 / ((double)sff * 1.702));
    const float mx0f   = (float)(-x0d);              // 30, exact
    const float n23x0f = (float)(23.0 * x0d);        // -690, exact
    const float rx0f   = (float)(1.0 / x0d);
    const float osf    = sff * 0.0078125f;

    const float4* xb = reinterpret_cast<const float4*>(xin);
    float4*       yb = reinterpret_cast<float4*>(yout);
    const size_t baseA = (size_t)rowA * V4;
    const size_t baseB = (size_t)rowB * V4;

    // Load both rows; interleaved lane-max chains.
    float4 keepA[PER], keepB[PER];
    float mxA = -3.402823466e38f, mxB = -3.402823466e38f;
#pragma unroll
    for (int i = 0; i < PER; ++i) {
        float4 a = xb[baseA + tx + i * TPB];
        float4 b = xb[baseB + tx + i * TPB];
        keepA[i] = a; keepB[i] = b;
        mxA = fmaxf(fmaxf(mxA, fmaxf(a.x, a.y)), fmaxf(a.z, a.w));
        mxB = fmaxf(fmaxf(mxB, fmaxf(b.x, b.y)), fmaxf(b.z, b.w));
    }
#pragma unroll
    for (int d = 32; d >= 1; d >>= 1) {
        mxA = fmaxf(mxA, __shfl_xor(mxA, d, 64));
        mxB = fmaxf(mxB, __shfl_xor(mxB, d, 64));
    }
    __shared__ float smx[ROWS][TPB / 64];
    if ((tx & 63) == 0) { smx[0][tx >> 6] = mxA; smx[1][tx >> 6] = mxB; }
    __syncthreads();                       // one barrier for both rows
    float xmA = smx[0][0], xmB = smx[1][0];
#pragma unroll
    for (int wv = 1; wv < TPB / 64; ++wv) {
        xmA = fmaxf(xmA, smx[0][wv]);
        xmB = fmaxf(xmB, smx[1][wv]);
    }

    const uint32_t emaxA =
        (uint32_t)eiarg_f(0.0f, xmA, rsff, mx0f, n23x0f, rx0f);
    const uint32_t emaxB =
        (uint32_t)eiarg_f(0.0f, xmB, rsff, mx0f, n23x0f, rx0f);

    uint32_t dmax = 0u;
    if (emaxA >= EMIN_FAST)
        row_pass<true >(keepA, yb, baseA, tx, xmA, rsff, mx0f, n23x0f, rx0f, emaxA, dmax);
    else
        row_pass<false>(keepA, yb, baseA, tx, xmA, rsff, mx0f, n23x0f, rx0f, emaxA, dmax);
    if (emaxB >= EMIN_FAST)
        row_pass<true >(keepB, yb, baseB, tx, xmB, rsff, mx0f, n23x0f, rx0f, emaxB, dmax);
    else
        row_pass<false>(keepB, yb, baseB, tx, xmB, rsff, mx0f, n23x0f, rx0f, emaxB, dmax);

    // dsig<=2 => W <= 2|x|/256 < WT2 for |x|<=12: fallback ~never fires.
    if (__any(dmax >= 3u)) {
#pragma unroll
        for (int i = 0; i < PER; ++i) {
            float4 a = keepA[i], b = keepB[i], oA, oB;
            oA.x = elem_full(a.x, xmA, rsff, mx0f, n23x0f, rx0f, emaxA);
            oA.y = elem_full(a.y, xmA, rsff, mx0f, n23x0f, rx0f, emaxA);
            oA.z = elem_full(a.z, xmA, rsff, mx0f, n23x0f, rx0f, emaxA);
            oA.w = elem_full(a.w, xmA, rsff, mx0f, n23x0f, rx0f, emaxA);
            oB.x = elem_full(b.x, xmB, rsff, mx0f, n23x0f, rx0f, emaxB);
            oB.y = elem_full(b.y, xmB, rsff, mx0f, n23x0f, rx0f, emaxB);
            oB.z = elem_full(b.z, xmB, rsff, mx0f, n23x0f, rx0f, emaxB);
            oB.w = elem_full(b.w, xmB, rsff, mx0f, n23x0f, rx0f, emaxB);
            yb[baseA + tx + i * TPB] = oA;
            yb[baseB + tx + i * TPB] = oB;
        }
    }

    if (blockIdx.x == 0 && tx == 0)
        yout[(size_t)nrow * H] = osf;
}

extern "C" void kernel_launch(void* const* d_in, const int* in_sizes, int n_in,
                              void* d_out, int out_size, void* d_ws, size_t ws_size,
                              hipStream_t stream) {
    const float* x  = (const float*)d_in[0];
    const float* sf = (const float*)d_in[1];
    float* out = (float*)d_out;
    const int total = in_sizes[0];       // 64*196*3072
    const int nrow  = total / H;         // 12544
    const int nblk  = nrow / ROWS;       // 6272
    ig_ivhedge_v20<<<nblk, TPB, 0, stream>>>(x, sf, out, nrow);
}